// Round 1
// baseline (5684.586 us; speedup 1.0000x reference)
//
#include <hip/hip_runtime.h>
#include <cstddef>

#define D 128

// ---------------- degree ----------------
__global__ void k_deg_init(float* __restrict__ degf, int n) {
  int i = blockIdx.x * 256 + threadIdx.x;
  if (i < n) degf[i] = 1.0f;  // self-loop
}

__global__ void k_deg_count(const int* __restrict__ ei, float* __restrict__ degf, int e) {
  int i = blockIdx.x * 256 + threadIdx.x;
  if (i < e) atomicAdd(&degf[ei[e + i]], 1.0f);  // dst = ei[1][i]
}

// ---------------- GEMM: T = act(X)@W ; Hinit = T * (1/deg) ----------------
// Block: 128 threads, 64 rows x 128 cols. Thread tile 8x8.
// X-tile transposed in LDS (pitch 68 -> only 2-way bank aliasing, free).
// W streamed from global (64KB, L2/L1-cached).
template <bool RELU_BIAS>
__global__ __launch_bounds__(128)
void k_gemm(const float* __restrict__ X, const float* __restrict__ W,
            const float* __restrict__ bias, const float* __restrict__ degf,
            float* __restrict__ T, float* __restrict__ Hinit, int n) {
  __shared__ __align__(16) float Xt[128 * 68];
  const int tid = threadIdx.x;
  const int row0 = blockIdx.x * 64;

  // load + transpose 64x128 tile (apply relu(x+b) of previous layer on the fly)
#pragma unroll
  for (int i = 0; i < 16; ++i) {
    int f = i * 128 + tid;        // float4 index in [64 rows x 32 quads]
    int rl = f >> 5;              // 0..63
    int k0 = (f & 31) * 4;        // 0..124
    int row = row0 + rl;
    float4 v = make_float4(0.f, 0.f, 0.f, 0.f);
    if (row < n) {
      v = *(const float4*)(X + (size_t)row * D + k0);
      if (RELU_BIAS) {
        float4 b = *(const float4*)(bias + k0);
        v.x = fmaxf(v.x + b.x, 0.f);
        v.y = fmaxf(v.y + b.y, 0.f);
        v.z = fmaxf(v.z + b.z, 0.f);
        v.w = fmaxf(v.w + b.w, 0.f);
      }
    }
    Xt[(k0 + 0) * 68 + rl] = v.x;
    Xt[(k0 + 1) * 68 + rl] = v.y;
    Xt[(k0 + 2) * 68 + rl] = v.z;
    Xt[(k0 + 3) * 68 + rl] = v.w;
  }
  __syncthreads();

  const int rg = tid >> 4;   // 0..7  -> rows rg*8..+8
  const int cg = tid & 15;   // 0..15 -> cols cg*8..+8
  float acc[8][8];
#pragma unroll
  for (int i = 0; i < 8; ++i)
#pragma unroll
    for (int j = 0; j < 8; ++j) acc[i][j] = 0.f;

  const float* Wp = W + cg * 8;
#pragma unroll 4
  for (int k = 0; k < 128; ++k) {
    float xv[8], wv[8];
    *(float4*)(xv)     = *(const float4*)(Xt + k * 68 + rg * 8);
    *(float4*)(xv + 4) = *(const float4*)(Xt + k * 68 + rg * 8 + 4);
    *(float4*)(wv)     = *(const float4*)(Wp + (size_t)k * D);
    *(float4*)(wv + 4) = *(const float4*)(Wp + (size_t)k * D + 4);
#pragma unroll
    for (int i = 0; i < 8; ++i)
#pragma unroll
      for (int j = 0; j < 8; ++j)
        acc[i][j] = fmaf(xv[i], wv[j], acc[i][j]);
  }

#pragma unroll
  for (int i = 0; i < 8; ++i) {
    int row = row0 + rg * 8 + i;
    if (row >= n) break;
    float dinv2 = 1.0f / degf[row];   // (deg^-1/2)^2 for self loop
    float4 a0 = make_float4(acc[i][0], acc[i][1], acc[i][2], acc[i][3]);
    float4 a1 = make_float4(acc[i][4], acc[i][5], acc[i][6], acc[i][7]);
    *(float4*)(T + (size_t)row * D + cg * 8)     = a0;
    *(float4*)(T + (size_t)row * D + cg * 8 + 4) = a1;
    float4 h0 = make_float4(a0.x * dinv2, a0.y * dinv2, a0.z * dinv2, a0.w * dinv2);
    float4 h1 = make_float4(a1.x * dinv2, a1.y * dinv2, a1.z * dinv2, a1.w * dinv2);
    *(float4*)(Hinit + (size_t)row * D + cg * 8)     = h0;
    *(float4*)(Hinit + (size_t)row * D + cg * 8 + 4) = h1;
  }
}

// ---------------- edge scatter (128-wide): H[dst] += T[src]*norm ----------------
// 32 lanes per edge, float4 per lane.
__global__ void k_edge_feat(const int* __restrict__ ei, const float* __restrict__ degf,
                            const float* __restrict__ T, float* __restrict__ H, int e) {
  long long g = (long long)blockIdx.x * 256 + threadIdx.x;
  long long eid = g >> 5;
  if (eid >= e) return;
  int fq = (int)(g & 31) * 4;
  int src = ei[eid];
  int dst = ei[e + eid];
  float norm = rsqrtf(degf[src] * degf[dst]);
  float4 v = *(const float4*)(T + (size_t)src * D + fq);
  float* o = H + (size_t)dst * D + fq;
  atomicAdd(o + 0, v.x * norm);
  atomicAdd(o + 1, v.y * norm);
  atomicAdd(o + 2, v.z * norm);
  atomicAdd(o + 3, v.w * norm);
}

// ---------------- final layer: s = relu(B+b1)@W2 ; o = s/deg ----------------
__global__ void k_dot(const float* __restrict__ B, const float* __restrict__ b1,
                      const float* __restrict__ W2, const float* __restrict__ degf,
                      float* __restrict__ s, float* __restrict__ o, int n) {
  int i = blockIdx.x * 256 + threadIdx.x;
  if (i >= n) return;
  float acc = 0.f;
#pragma unroll 8
  for (int k = 0; k < 32; ++k) {
    float4 h = *(const float4*)(B + (size_t)i * D + k * 4);
    float4 bb = *(const float4*)(b1 + k * 4);
    float4 w = *(const float4*)(W2 + k * 4);
    acc += fmaxf(h.x + bb.x, 0.f) * w.x;
    acc += fmaxf(h.y + bb.y, 0.f) * w.y;
    acc += fmaxf(h.z + bb.z, 0.f) * w.z;
    acc += fmaxf(h.w + bb.w, 0.f) * w.w;
  }
  s[i] = acc;
  o[i] = acc / degf[i];
}

__global__ void k_edge_scalar(const int* __restrict__ ei, const float* __restrict__ degf,
                              const float* __restrict__ s, float* __restrict__ o, int e) {
  int i = blockIdx.x * 256 + threadIdx.x;
  if (i >= e) return;
  int src = ei[i];
  int dst = ei[e + i];
  float norm = rsqrtf(degf[src] * degf[dst]);
  atomicAdd(&o[dst], s[src] * norm);
}

__global__ void k_final(const float* __restrict__ o, const float* __restrict__ b2,
                        float* __restrict__ out, int n) {
  int i = blockIdx.x * 256 + threadIdx.x;
  if (i >= n) return;
  float v = o[i] + b2[0];
  out[i] = 1.f / (1.f + expf(-v));
}

// ---------------- launch ----------------
extern "C" void kernel_launch(void* const* d_in, const int* in_sizes, int n_in,
                              void* d_out, int out_size, void* d_ws, size_t ws_size,
                              hipStream_t stream) {
  const float* x  = (const float*)d_in[0];
  const int*   ei = (const int*)d_in[1];   // int64 in source collapses to int32 (JAX x64 off)
  const float* W0 = (const float*)d_in[2];
  const float* b0 = (const float*)d_in[3];
  const float* W1 = (const float*)d_in[4];
  const float* b1 = (const float*)d_in[5];
  const float* W2 = (const float*)d_in[6];
  const float* b2 = (const float*)d_in[7];
  float* out = (float*)d_out;

  const int n = in_sizes[0] / D;
  const int e = in_sizes[1] / 2;

  float* ws = (float*)d_ws;
  float* degf = ws;                                     // n floats
  float* A = ws + (((size_t)n + 1023) / 1024) * 1024;   // n*D floats (t = X@W)
  float* B = A + (size_t)n * D;                         // n*D floats (aggregated)
  float* s = A;                                         // reuse A after last 128-wide agg
  float* o = A + (((size_t)n + 1023) / 1024) * 1024;

  const int g256n = (n + 255) / 256;
  const int g256e = (e + 255) / 256;
  const int ggemm = (n + 63) / 64;
  const int gedge = (int)(((long long)e * 32 + 255) / 256);

  // degree (incl. self loop)
  k_deg_init<<<g256n, 256, 0, stream>>>(degf, n);
  k_deg_count<<<g256e, 256, 0, stream>>>(ei, degf, e);

  // layer 0: A = x@W0 ; B = A/deg ; B += A[src]*norm
  k_gemm<false><<<ggemm, 128, 0, stream>>>(x, W0, nullptr, degf, A, B, n);
  k_edge_feat<<<gedge, 256, 0, stream>>>(ei, degf, A, B, e);

  // layer 1: A = relu(B+b0)@W1 ; B = A/deg (in-place safe) ; B += A[src]*norm
  k_gemm<true><<<ggemm, 128, 0, stream>>>(B, W1, b0, degf, A, B, n);
  k_edge_feat<<<gedge, 256, 0, stream>>>(ei, degf, A, B, e);

  // layer 2: s = relu(B+b1)@W2 ; o = s/deg ; o += s[src]*norm ; out = sigmoid(o+b2)
  k_dot<<<g256n, 256, 0, stream>>>(B, b1, W2, degf, s, o, n);
  k_edge_scalar<<<g256e, 256, 0, stream>>>(ei, degf, s, o, e);
  k_final<<<g256n, 256, 0, stream>>>(o, b2, out, n);
}

// Round 2
// 603.549 us; speedup vs baseline: 9.4186x; 9.4186x over previous
//
#include <hip/hip_runtime.h>
#include <cstddef>

#define D 128

// ================= CSR build =================
__global__ void k_zero(int* __restrict__ p, int n) {
  int i = blockIdx.x * 256 + threadIdx.x;
  if (i < n) p[i] = 0;
}

__global__ void k_count(const int* __restrict__ ei, int* __restrict__ cnt, int e) {
  int i = blockIdx.x * 256 + threadIdx.x;
  if (i < e) atomicAdd(&cnt[ei[e + i]], 1);  // dst = ei[1][i]
}

__global__ void k_dinv(const int* __restrict__ cnt, float* __restrict__ dinv, int n) {
  int i = blockIdx.x * 256 + threadIdx.x;
  if (i < n) dinv[i] = rsqrtf((float)cnt[i] + 1.0f);  // +1 self loop
}

// exclusive scan, 3 stages (n <= 256*1024)
__global__ void k_scan1(const int* __restrict__ cnt, int* __restrict__ off,
                        int* __restrict__ bsum, int n) {
  __shared__ int s[256];
  int t = threadIdx.x;
  int i = blockIdx.x * 256 + t;
  int v = (i < n) ? cnt[i] : 0;
  s[t] = v;
  __syncthreads();
#pragma unroll
  for (int d = 1; d < 256; d <<= 1) {
    int x = (t >= d) ? s[t - d] : 0;
    __syncthreads();
    s[t] += x;
    __syncthreads();
  }
  if (i < n) off[i] = s[t] - v;            // exclusive within block
  if (t == 255) bsum[blockIdx.x] = s[255]; // block total
}

__global__ void k_scan2(int* __restrict__ bsum, int nb) {
  __shared__ int s[1024];
  int t = threadIdx.x;
  int v = (t < nb) ? bsum[t] : 0;
  s[t] = v;
  __syncthreads();
  for (int d = 1; d < 1024; d <<= 1) {
    int x = (t >= d) ? s[t - d] : 0;
    __syncthreads();
    s[t] += x;
    __syncthreads();
  }
  if (t < nb) bsum[t] = s[t] - v;          // exclusive block offsets
}

__global__ void k_scan3(int* __restrict__ off, const int* __restrict__ bsum, int n, int e) {
  int i = blockIdx.x * 256 + threadIdx.x;
  if (i < n) off[i] += bsum[i >> 8];
  if (i == 0) off[n] = e;
}

__global__ void k_fill(const int* __restrict__ ei, const int* __restrict__ off,
                       int* __restrict__ fill, int* __restrict__ csr, int e) {
  int i = blockIdx.x * 256 + threadIdx.x;
  if (i >= e) return;
  int src = ei[i];
  int dst = ei[e + i];
  int pos = off[dst] + atomicAdd(&fill[dst], 1);
  csr[pos] = src;
}

// ================= GEMM: As = act(X)@W * dinv[row] =================
// Block: 128 threads -> 64 rows x 128 cols, 8x8 per thread.
template <bool RELU_BIAS>
__global__ __launch_bounds__(128)
void k_gemm(const float* __restrict__ X, const float* __restrict__ W,
            const float* __restrict__ bias, const float* __restrict__ dinv,
            float* __restrict__ As, int n) {
  __shared__ __align__(16) float Xt[128 * 68];
  const int tid = threadIdx.x;
  const int row0 = blockIdx.x * 64;

#pragma unroll
  for (int i = 0; i < 16; ++i) {
    int f = i * 128 + tid;
    int rl = f >> 5;
    int k0 = (f & 31) * 4;
    int row = row0 + rl;
    float4 v = make_float4(0.f, 0.f, 0.f, 0.f);
    if (row < n) {
      v = *(const float4*)(X + (size_t)row * D + k0);
      if (RELU_BIAS) {
        float4 b = *(const float4*)(bias + k0);
        v.x = fmaxf(v.x + b.x, 0.f);
        v.y = fmaxf(v.y + b.y, 0.f);
        v.z = fmaxf(v.z + b.z, 0.f);
        v.w = fmaxf(v.w + b.w, 0.f);
      }
    }
    Xt[(k0 + 0) * 68 + rl] = v.x;
    Xt[(k0 + 1) * 68 + rl] = v.y;
    Xt[(k0 + 2) * 68 + rl] = v.z;
    Xt[(k0 + 3) * 68 + rl] = v.w;
  }
  __syncthreads();

  const int rg = tid >> 4;
  const int cg = tid & 15;
  float acc[8][8];
#pragma unroll
  for (int i = 0; i < 8; ++i)
#pragma unroll
    for (int j = 0; j < 8; ++j) acc[i][j] = 0.f;

  const float* Wp = W + cg * 8;
#pragma unroll 4
  for (int k = 0; k < 128; ++k) {
    float xv[8], wv[8];
    *(float4*)(xv)     = *(const float4*)(Xt + k * 68 + rg * 8);
    *(float4*)(xv + 4) = *(const float4*)(Xt + k * 68 + rg * 8 + 4);
    *(float4*)(wv)     = *(const float4*)(Wp + (size_t)k * D);
    *(float4*)(wv + 4) = *(const float4*)(Wp + (size_t)k * D + 4);
#pragma unroll
    for (int i = 0; i < 8; ++i)
#pragma unroll
      for (int j = 0; j < 8; ++j)
        acc[i][j] = fmaf(xv[i], wv[j], acc[i][j]);
  }

#pragma unroll
  for (int i = 0; i < 8; ++i) {
    int row = row0 + rg * 8 + i;
    if (row >= n) break;
    float di = dinv[row];
    float4 a0 = make_float4(acc[i][0] * di, acc[i][1] * di, acc[i][2] * di, acc[i][3] * di);
    float4 a1 = make_float4(acc[i][4] * di, acc[i][5] * di, acc[i][6] * di, acc[i][7] * di);
    *(float4*)(As + (size_t)row * D + cg * 8)     = a0;
    *(float4*)(As + (size_t)row * D + cg * 8 + 4) = a1;
  }
}

// ================= gather aggregate (128-wide) =================
// One wave per node; lane handles 2 feature cols.
// B[i] = dinv[i] * (As[i] + sum_j As[csr[j]])
__global__ __launch_bounds__(256)
void k_gather(const int* __restrict__ off, const int* __restrict__ csr,
              const float* __restrict__ dinv, const float* __restrict__ As,
              float* __restrict__ B, int n) {
  int wid = (int)(((long long)blockIdx.x * 256 + threadIdx.x) >> 6);
  int lane = threadIdx.x & 63;
  if (wid >= n) return;
  int o0 = off[wid], o1 = off[wid + 1];
  const int c = lane * 2;
  float2 acc = *(const float2*)(As + (size_t)wid * D + c);  // self term (pre-scaled)
  for (int j0 = o0; j0 < o1; j0 += 64) {
    int sj = 0;
    if (j0 + lane < o1) sj = csr[j0 + lane];
    int m = min(64, o1 - j0);
    for (int t = 0; t < m; ++t) {
      int s = __shfl(sj, t);
      float2 v = *(const float2*)(As + (size_t)s * D + c);
      acc.x += v.x;
      acc.y += v.y;
    }
  }
  float di = dinv[wid];
  acc.x *= di;
  acc.y *= di;
  *(float2*)(B + (size_t)wid * D + c) = acc;
}

// ================= final layer =================
// ss[i] = dinv[i] * (relu(B[i]+b1) . W2)
__global__ void k_dot(const float* __restrict__ B, const float* __restrict__ b1,
                      const float* __restrict__ W2, const float* __restrict__ dinv,
                      float* __restrict__ ss, int n) {
  int i = blockIdx.x * 256 + threadIdx.x;
  if (i >= n) return;
  float acc = 0.f;
#pragma unroll 8
  for (int k = 0; k < 32; ++k) {
    float4 h = *(const float4*)(B + (size_t)i * D + k * 4);
    float4 bb = *(const float4*)(b1 + k * 4);
    float4 w = *(const float4*)(W2 + k * 4);
    acc += fmaxf(h.x + bb.x, 0.f) * w.x;
    acc += fmaxf(h.y + bb.y, 0.f) * w.y;
    acc += fmaxf(h.z + bb.z, 0.f) * w.z;
    acc += fmaxf(h.w + bb.w, 0.f) * w.w;
  }
  ss[i] = acc * dinv[i];
}

// out[i] = sigmoid(dinv[i]*(ss[i] + sum ss[src]) + b2)
__global__ void k_gather_scalar(const int* __restrict__ off, const int* __restrict__ csr,
                                const float* __restrict__ dinv, const float* __restrict__ ss,
                                const float* __restrict__ b2, float* __restrict__ out, int n) {
  int i = blockIdx.x * 256 + threadIdx.x;
  if (i >= n) return;
  float acc = ss[i];
  int o0 = off[i], o1 = off[i + 1];
  for (int j = o0; j < o1; ++j) acc += ss[csr[j]];
  float v = acc * dinv[i] + b2[0];
  out[i] = 1.f / (1.f + expf(-v));
}

// ================= launch =================
extern "C" void kernel_launch(void* const* d_in, const int* in_sizes, int n_in,
                              void* d_out, int out_size, void* d_ws, size_t ws_size,
                              hipStream_t stream) {
  const float* x  = (const float*)d_in[0];
  const int*   ei = (const int*)d_in[1];   // int64 in source collapses to int32 (JAX x64 off)
  const float* W0 = (const float*)d_in[2];
  const float* b0 = (const float*)d_in[3];
  const float* W1 = (const float*)d_in[4];
  const float* b1 = (const float*)d_in[5];
  const float* W2 = (const float*)d_in[6];
  const float* b2 = (const float*)d_in[7];
  float* out = (float*)d_out;

  const int n = in_sizes[0] / D;
  const int e = in_sizes[1] / 2;
  const size_t np = ((size_t)n + 256) / 256 * 256;  // n+1 fits, 256-aligned

  // workspace layout (floats):
  float* ws = (float*)d_ws;
  int*   off  = (int*)ws;                 // np ints (holds n+1)
  float* dinv = ws + np;                  // np
  float* ss   = ws + 2 * np;              // np (aliased: bsum during scan)
  int*   csr  = (int*)(ws + 3 * np);      // e ints
  float* As   = ws + 3 * np + e;          // n*D
  float* B    = As + (size_t)n * D;       // n*D
  int*   cnt  = (int*)B;                  // aliased onto B (build phase only)
  int*   fill = cnt + np;
  int*   bsum = (int*)ss;

  const int g256n = (n + 255) / 256;
  const int g256e = (e + 255) / 256;
  const int nb = (n + 255) / 256;         // scan blocks (<=1024)
  const int ggemm = (n + 63) / 64;
  const int ggath = (int)(((long long)n * 64 + 255) / 256);

  // ---- CSR build (dst-indexed), reused by all 3 layers ----
  k_zero<<<(2 * (int)np + 255) / 256, 256, 0, stream>>>(cnt, 2 * (int)np);  // cnt+fill
  k_count<<<g256e, 256, 0, stream>>>(ei, cnt, e);
  k_dinv<<<g256n, 256, 0, stream>>>(cnt, dinv, n);
  k_scan1<<<nb, 256, 0, stream>>>(cnt, off, bsum, n);
  k_scan2<<<1, 1024, 0, stream>>>(bsum, nb);
  k_scan3<<<g256n, 256, 0, stream>>>(off, bsum, n, e);
  k_fill<<<g256e, 256, 0, stream>>>(ei, off, fill, csr, e);

  // ---- layer 0: As = (x@W0)*dinv ; B = dinv*(As_self + sum As[src]) ----
  k_gemm<false><<<ggemm, 128, 0, stream>>>(x, W0, nullptr, dinv, As, n);
  k_gather<<<ggath, 256, 0, stream>>>(off, csr, dinv, As, B, n);

  // ---- layer 1: As = (relu(B+b0)@W1)*dinv ; B = gather ----
  k_gemm<true><<<ggemm, 128, 0, stream>>>(B, W1, b0, dinv, As, n);
  k_gather<<<ggath, 256, 0, stream>>>(off, csr, dinv, As, B, n);

  // ---- layer 2 (scalar): ss = dinv*(relu(B+b1).W2) ; out = sigmoid(...) ----
  k_dot<<<g256n, 256, 0, stream>>>(B, b1, W2, dinv, ss, n);
  k_gather_scalar<<<g256n, 256, 0, stream>>>(off, csr, dinv, ss, b2, out, n);
}

// Round 3
// 460.769 us; speedup vs baseline: 12.3372x; 1.3099x over previous
//
#include <hip/hip_runtime.h>
#include <cstddef>

#define D 128
typedef unsigned int uint;
typedef unsigned short ushort;

// ---- bf16 helpers (RNE) ----
static __device__ __forceinline__ uint bf16r(float x) {
  uint u = __float_as_uint(x);
  return (u + 0x7fffu + ((u >> 16) & 1u)) >> 16;
}
static __device__ __forceinline__ uint pack2(float a, float b) {
  return bf16r(a) | (bf16r(b) << 16);
}
static __device__ __forceinline__ void acc_bf16x8(const uint4 v, float* a) {
  a[0] += __uint_as_float(v.x << 16);
  a[1] += __uint_as_float(v.x & 0xffff0000u);
  a[2] += __uint_as_float(v.y << 16);
  a[3] += __uint_as_float(v.y & 0xffff0000u);
  a[4] += __uint_as_float(v.z << 16);
  a[5] += __uint_as_float(v.z & 0xffff0000u);
  a[6] += __uint_as_float(v.w << 16);
  a[7] += __uint_as_float(v.w & 0xffff0000u);
}

// ================= CSR build =================
__global__ void k_zero(int* __restrict__ p, int n) {
  int i = blockIdx.x * 256 + threadIdx.x;
  if (i < n) p[i] = 0;
}

__global__ void k_count(const int* __restrict__ ei, int* __restrict__ cnt, int e) {
  int i = blockIdx.x * 256 + threadIdx.x;
  if (i < e) atomicAdd(&cnt[ei[e + i]], 1);  // dst = ei[1][i]
}

__global__ void k_dinv(const int* __restrict__ cnt, float* __restrict__ dinv, int n) {
  int i = blockIdx.x * 256 + threadIdx.x;
  if (i < n) dinv[i] = rsqrtf((float)cnt[i] + 1.0f);  // +1 self loop
}

__global__ void k_scan1(const int* __restrict__ cnt, int* __restrict__ off,
                        int* __restrict__ bsum, int n) {
  __shared__ int s[256];
  int t = threadIdx.x;
  int i = blockIdx.x * 256 + t;
  int v = (i < n) ? cnt[i] : 0;
  s[t] = v;
  __syncthreads();
#pragma unroll
  for (int d = 1; d < 256; d <<= 1) {
    int x = (t >= d) ? s[t - d] : 0;
    __syncthreads();
    s[t] += x;
    __syncthreads();
  }
  if (i < n) off[i] = s[t] - v;
  if (t == 255) bsum[blockIdx.x] = s[255];
}

__global__ void k_scan2(int* __restrict__ bsum, int nb) {
  __shared__ int s[1024];
  int t = threadIdx.x;
  int v = (t < nb) ? bsum[t] : 0;
  s[t] = v;
  __syncthreads();
  for (int d = 1; d < 1024; d <<= 1) {
    int x = (t >= d) ? s[t - d] : 0;
    __syncthreads();
    s[t] += x;
    __syncthreads();
  }
  if (t < nb) bsum[t] = s[t] - v;
}

__global__ void k_scan3(int* __restrict__ off, const int* __restrict__ bsum, int n, int e) {
  int i = blockIdx.x * 256 + threadIdx.x;
  if (i < n) off[i] += bsum[i >> 8];
  if (i == 0) off[n] = e;
}

__global__ void k_fill(const int* __restrict__ ei, const int* __restrict__ off,
                       int* __restrict__ fill, int* __restrict__ csr, int e) {
  int i = blockIdx.x * 256 + threadIdx.x;
  if (i >= e) return;
  int src = ei[i];
  int dst = ei[e + i];
  int pos = off[dst] + atomicAdd(&fill[dst], 1);
  csr[pos] = src;
}

// ================= GEMM: Asb(bf16) = (act(X)@W) * dinv[row] =================
template <bool RELU_BIAS>
__global__ __launch_bounds__(128)
void k_gemm(const float* __restrict__ X, const float* __restrict__ W,
            const float* __restrict__ bias, const float* __restrict__ dinv,
            ushort* __restrict__ Asb, int n) {
  __shared__ __align__(16) float Xt[128 * 68];
  const int tid = threadIdx.x;
  const int row0 = blockIdx.x * 64;

#pragma unroll
  for (int i = 0; i < 16; ++i) {
    int f = i * 128 + tid;
    int rl = f >> 5;
    int k0 = (f & 31) * 4;
    int row = row0 + rl;
    float4 v = make_float4(0.f, 0.f, 0.f, 0.f);
    if (row < n) {
      v = *(const float4*)(X + (size_t)row * D + k0);
      if (RELU_BIAS) {
        float4 b = *(const float4*)(bias + k0);
        v.x = fmaxf(v.x + b.x, 0.f);
        v.y = fmaxf(v.y + b.y, 0.f);
        v.z = fmaxf(v.z + b.z, 0.f);
        v.w = fmaxf(v.w + b.w, 0.f);
      }
    }
    Xt[(k0 + 0) * 68 + rl] = v.x;
    Xt[(k0 + 1) * 68 + rl] = v.y;
    Xt[(k0 + 2) * 68 + rl] = v.z;
    Xt[(k0 + 3) * 68 + rl] = v.w;
  }
  __syncthreads();

  const int rg = tid >> 4;
  const int cg = tid & 15;
  float acc[8][8];
#pragma unroll
  for (int i = 0; i < 8; ++i)
#pragma unroll
    for (int j = 0; j < 8; ++j) acc[i][j] = 0.f;

  const float* Wp = W + cg * 8;
#pragma unroll 4
  for (int k = 0; k < 128; ++k) {
    float xv[8], wv[8];
    *(float4*)(xv)     = *(const float4*)(Xt + k * 68 + rg * 8);
    *(float4*)(xv + 4) = *(const float4*)(Xt + k * 68 + rg * 8 + 4);
    *(float4*)(wv)     = *(const float4*)(Wp + (size_t)k * D);
    *(float4*)(wv + 4) = *(const float4*)(Wp + (size_t)k * D + 4);
#pragma unroll
    for (int i = 0; i < 8; ++i)
#pragma unroll
      for (int j = 0; j < 8; ++j)
        acc[i][j] = fmaf(xv[i], wv[j], acc[i][j]);
  }

#pragma unroll
  for (int i = 0; i < 8; ++i) {
    int row = row0 + rg * 8 + i;
    if (row >= n) break;
    float di = dinv[row];
    uint4 w;
    w.x = pack2(acc[i][0] * di, acc[i][1] * di);
    w.y = pack2(acc[i][2] * di, acc[i][3] * di);
    w.z = pack2(acc[i][4] * di, acc[i][5] * di);
    w.w = pack2(acc[i][6] * di, acc[i][7] * di);
    *(uint4*)(Asb + (size_t)row * D + cg * 8) = w;
  }
}

// ================= gather aggregate =================
// One wave per node. Quarter-wave (16 lanes) covers a 128-col bf16 row
// (8 cols/lane, 16B dwordx4); 4 edges processed per step, unroll 4 -> ~16
// row-loads in flight. f32 accumulate.
// FUSE_DOT: epilogue computes ss[i]=dinv*(relu(B+b1).W2) instead of storing B.
template <bool FUSE_DOT>
__global__ __launch_bounds__(256)
void k_gather(const int* __restrict__ off, const int* __restrict__ csr,
              const float* __restrict__ dinv, const ushort* __restrict__ Asb,
              float* __restrict__ B, const float* __restrict__ b1,
              const float* __restrict__ W2, float* __restrict__ ss, int n) {
  const int wid = blockIdx.x * 4 + (threadIdx.x >> 6);
  if (wid >= n) return;
  const int lane = threadIdx.x & 63;
  const int q = lane >> 4;     // quarter 0..3
  const int li = lane & 15;    // 0..15
  const int c = li << 3;       // col base (8 cols)

  float a[8];
  if (q == 0) {  // self term (pre-scaled by dinv[row] in GEMM)
    uint4 sv = *(const uint4*)(Asb + (size_t)wid * D + c);
#pragma unroll
    for (int k = 0; k < 8; ++k) a[k] = 0.f;
    acc_bf16x8(sv, a);
  } else {
#pragma unroll
    for (int k = 0; k < 8; ++k) a[k] = 0.f;
  }

  const int o0 = off[wid], o1 = off[wid + 1];
  for (int j0 = o0; j0 < o1; j0 += 64) {
    int sj = 0;
    if (j0 + lane < o1) sj = csr[j0 + lane];
    const int m = min(64, o1 - j0);
    const int nst = (m + 3) >> 2;
#pragma unroll 4
    for (int t = 0; t < nst; ++t) {
      int idx = (t << 2) + q;
      int s = __shfl(sj, idx);
      if (idx < m) {
        uint4 v = *(const uint4*)(Asb + (size_t)s * D + c);
        acc_bf16x8(v, a);
      }
    }
  }

  // merge quarters
#pragma unroll
  for (int k = 0; k < 8; ++k) {
    a[k] += __shfl_xor(a[k], 16);
    a[k] += __shfl_xor(a[k], 32);
  }

  const float di = dinv[wid];
  if (FUSE_DOT) {
    float4 bb0 = *(const float4*)(b1 + c);
    float4 bb1 = *(const float4*)(b1 + c + 4);
    float4 w0 = *(const float4*)(W2 + c);
    float4 w1 = *(const float4*)(W2 + c + 4);
    float p = 0.f;
    p += fmaxf(a[0] * di + bb0.x, 0.f) * w0.x;
    p += fmaxf(a[1] * di + bb0.y, 0.f) * w0.y;
    p += fmaxf(a[2] * di + bb0.z, 0.f) * w0.z;
    p += fmaxf(a[3] * di + bb0.w, 0.f) * w0.w;
    p += fmaxf(a[4] * di + bb1.x, 0.f) * w1.x;
    p += fmaxf(a[5] * di + bb1.y, 0.f) * w1.y;
    p += fmaxf(a[6] * di + bb1.z, 0.f) * w1.z;
    p += fmaxf(a[7] * di + bb1.w, 0.f) * w1.w;
    p += __shfl_xor(p, 1);
    p += __shfl_xor(p, 2);
    p += __shfl_xor(p, 4);
    p += __shfl_xor(p, 8);
    if (lane == 0) ss[wid] = p * di;
  } else {
    if (lane < 16) {
      float4 o0v = make_float4(a[0] * di, a[1] * di, a[2] * di, a[3] * di);
      float4 o1v = make_float4(a[4] * di, a[5] * di, a[6] * di, a[7] * di);
      *(float4*)(B + (size_t)wid * D + c)     = o0v;
      *(float4*)(B + (size_t)wid * D + c + 4) = o1v;
    }
  }
}

// ================= scalar gather + sigmoid =================
__global__ void k_gather_scalar(const int* __restrict__ off, const int* __restrict__ csr,
                                const float* __restrict__ dinv, const float* __restrict__ ss,
                                const float* __restrict__ b2, float* __restrict__ out, int n) {
  int i = blockIdx.x * 256 + threadIdx.x;
  if (i >= n) return;
  float acc = ss[i];
  int j = off[i], o1 = off[i + 1];
  float a0 = 0.f, a1 = 0.f, a2 = 0.f, a3 = 0.f;
  for (; j + 4 <= o1; j += 4) {
    int s0 = csr[j], s1 = csr[j + 1], s2 = csr[j + 2], s3 = csr[j + 3];
    a0 += ss[s0];
    a1 += ss[s1];
    a2 += ss[s2];
    a3 += ss[s3];
  }
  for (; j < o1; ++j) a0 += ss[csr[j]];
  acc += (a0 + a1) + (a2 + a3);
  float v = acc * dinv[i] + b2[0];
  out[i] = 1.f / (1.f + expf(-v));
}

// ================= launch =================
extern "C" void kernel_launch(void* const* d_in, const int* in_sizes, int n_in,
                              void* d_out, int out_size, void* d_ws, size_t ws_size,
                              hipStream_t stream) {
  const float* x  = (const float*)d_in[0];
  const int*   ei = (const int*)d_in[1];   // int64 in source collapses to int32 (JAX x64 off)
  const float* W0 = (const float*)d_in[2];
  const float* b0 = (const float*)d_in[3];
  const float* W1 = (const float*)d_in[4];
  const float* b1 = (const float*)d_in[5];
  const float* W2 = (const float*)d_in[6];
  const float* b2 = (const float*)d_in[7];
  float* out = (float*)d_out;

  const int n = in_sizes[0] / D;
  const int e = in_sizes[1] / 2;
  const size_t np = ((size_t)n + 256) / 256 * 256;  // holds n+1, 256-aligned

  float* ws = (float*)d_ws;
  int*    off  = (int*)ws;                     // np ints
  float*  dinv = ws + np;                      // np
  float*  ss   = ws + 2 * np;                  // np (aliased: bsum during scan)
  int*    csr  = (int*)(ws + 3 * np);          // e ints
  ushort* Asb  = (ushort*)(ws + 3 * np + e);   // n*D bf16 (n*D/2 floats)
  float*  B    = ws + 3 * np + e + (size_t)n * D / 2;  // n*D floats
  int*    cnt  = (int*)B;                      // build-phase alias
  int*    fill = cnt + np;
  int*    bsum = (int*)ss;

  const int g256n = (n + 255) / 256;
  const int g256e = (e + 255) / 256;
  const int nb = (n + 255) / 256;
  const int ggemm = (n + 63) / 64;
  const int ggath = (n + 3) / 4;

  // ---- CSR build (dst-indexed), reused by all 3 layers ----
  k_zero<<<(2 * (int)np + 255) / 256, 256, 0, stream>>>(cnt, 2 * (int)np);
  k_count<<<g256e, 256, 0, stream>>>(ei, cnt, e);
  k_dinv<<<g256n, 256, 0, stream>>>(cnt, dinv, n);
  k_scan1<<<nb, 256, 0, stream>>>(cnt, off, bsum, n);
  k_scan2<<<1, 1024, 0, stream>>>(bsum, nb);
  k_scan3<<<g256n, 256, 0, stream>>>(off, bsum, n, e);
  k_fill<<<g256e, 256, 0, stream>>>(ei, off, fill, csr, e);

  // ---- layer 0 ----
  k_gemm<false><<<ggemm, 128, 0, stream>>>(x, W0, nullptr, dinv, Asb, n);
  k_gather<false><<<ggath, 256, 0, stream>>>(off, csr, dinv, Asb, B, nullptr, nullptr, nullptr, n);

  // ---- layer 1 ----
  k_gemm<true><<<ggemm, 128, 0, stream>>>(B, W1, b0, dinv, Asb, n);
  // ---- layer 2 GEMV fused into gather epilogue ----
  k_gather<true><<<ggath, 256, 0, stream>>>(off, csr, dinv, Asb, nullptr, b1, W2, ss, n);

  // ---- scalar aggregate + sigmoid ----
  k_gather_scalar<<<g256n, 256, 0, stream>>>(off, csr, dinv, ss, b2, out, n);
}

// Round 4
// 347.557 us; speedup vs baseline: 16.3558x; 1.3257x over previous
//
#include <hip/hip_runtime.h>
#include <cstddef>

#define D 128
#define BW_LOG 11
#define BW 2048            // nodes per bucket (NB = ceil(n/BW) <= 256 required)
#define CHUNK 8192         // edges per bscatter/bhist block
typedef unsigned int uint;
typedef unsigned short ushort;

// ---- bf16 helpers (RNE) ----
static __device__ __forceinline__ uint bf16r(float x) {
  uint u = __float_as_uint(x);
  return (u + 0x7fffu + ((u >> 16) & 1u)) >> 16;
}
static __device__ __forceinline__ uint pack2(float a, float b) {
  return bf16r(a) | (bf16r(b) << 16);
}
static __device__ __forceinline__ void acc_bf16x8(const uint4 v, float* a) {
  a[0] += __uint_as_float(v.x << 16);
  a[1] += __uint_as_float(v.x & 0xffff0000u);
  a[2] += __uint_as_float(v.y << 16);
  a[3] += __uint_as_float(v.y & 0xffff0000u);
  a[4] += __uint_as_float(v.z << 16);
  a[5] += __uint_as_float(v.z & 0xffff0000u);
  a[6] += __uint_as_float(v.w << 16);
  a[7] += __uint_as_float(v.w & 0xffff0000u);
}

// ================= bucketed CSR build =================
__global__ void k_bzero(int* __restrict__ bcnt, int nb) {
  int t = threadIdx.x;
  if (t < nb) bcnt[t] = 0;
}

// global per-bucket histogram of dst>>BW_LOG
__global__ __launch_bounds__(512)
void k_bhist(const int* __restrict__ dstA, int* __restrict__ bcnt, int e, int nb) {
  __shared__ int h[256];
  int t = threadIdx.x;
  if (t < nb) h[t] = 0;
  __syncthreads();
  int base = blockIdx.x * CHUNK;
  int m = min(CHUNK, e - base);
  for (int i = t; i < m; i += 512) atomicAdd(&h[dstA[base + i] >> BW_LOG], 1);
  __syncthreads();
  if (t < nb && h[t]) atomicAdd(&bcnt[t], h[t]);
}

// exclusive scan of bucket counts -> bbase, cursor; off[n]=e
__global__ void k_bscan(const int* __restrict__ bcnt, int* __restrict__ bbase,
                        int* __restrict__ cursor, int* __restrict__ off,
                        int nb, int n, int e) {
  __shared__ int s[256];
  int t = threadIdx.x;
  int v = (t < nb) ? bcnt[t] : 0;
  s[t] = v;
  __syncthreads();
  for (int d = 1; d < 256; d <<= 1) {
    int x = (t >= d) ? s[t - d] : 0;
    __syncthreads();
    s[t] += x;
    __syncthreads();
  }
  if (t < nb) {
    int b = s[t] - v;
    bbase[t] = b;
    cursor[t] = b;
  }
  if (t == 0) {
    bbase[nb] = e;
    off[n] = e;
  }
}

// bin CHUNK edges into LDS by bucket, copy out coalesced as packed src|dstlow<<17
__global__ __launch_bounds__(512)
void k_bscatter(const int* __restrict__ ei, int* __restrict__ cursor,
                int* __restrict__ pk, int e, int nb) {
  __shared__ int h[256], lbase[256], gpos[256], lcur[256], s2[256];
  __shared__ int staged[CHUNK];
  int t = threadIdx.x;
  if (t < nb) h[t] = 0;
  __syncthreads();
  int base = blockIdx.x * CHUNK;
  int m = min(CHUNK, e - base);
  int sv[16], dv[16];
#pragma unroll
  for (int k = 0; k < 16; ++k) {
    int i = t + k * 512;
    sv[k] = 0; dv[k] = 0;
    if (i < m) {
      sv[k] = ei[base + i];
      dv[k] = ei[e + base + i];
      atomicAdd(&h[dv[k] >> BW_LOG], 1);
    }
  }
  __syncthreads();
  if (t < 256) s2[t] = (t < nb) ? h[t] : 0;
  __syncthreads();
  for (int d = 1; d < 256; d <<= 1) {
    int x = 0;
    if (t < 256 && t >= d) x = s2[t - d];
    __syncthreads();
    if (t < 256) s2[t] += x;
    __syncthreads();
  }
  if (t < nb) {
    lbase[t] = s2[t] - h[t];
    lcur[t] = s2[t] - h[t];
    gpos[t] = h[t] ? atomicAdd(&cursor[t], h[t]) : 0;
  }
  __syncthreads();
#pragma unroll
  for (int k = 0; k < 16; ++k) {
    int i = t + k * 512;
    if (i < m) {
      int b = dv[k] >> BW_LOG;
      int p = atomicAdd(&lcur[b], 1);
      staged[p] = sv[k] | ((dv[k] & (BW - 1)) << 17);
    }
  }
  __syncthreads();
  for (int b = 0; b < nb; ++b) {
    int cnt = h[b], lb = lbase[b], gp = gpos[b];
    for (int i = t; i < cnt; i += 512) pk[gp + i] = staged[lb + i];
  }
}

// one block per bucket: per-dst counts -> off/dinv; scatter csr within bucket window
__global__ __launch_bounds__(1024)
void k_bfinal(const int* __restrict__ bbase, const int* __restrict__ pk,
              int* __restrict__ off, float* __restrict__ dinv,
              int* __restrict__ csr, int n, int nb) {
  __shared__ int sc[BW];
  __shared__ int lcur[BW];
  const int b = blockIdx.x;
  const int t = threadIdx.x;
  const int e0 = bbase[b], e1 = bbase[b + 1];
  const int node0 = b << BW_LOG;
  sc[t] = 0; sc[t + 1024] = 0;
  lcur[t] = 0; lcur[t + 1024] = 0;
  __syncthreads();
  for (int i = e0 + t; i < e1; i += 1024) atomicAdd(&sc[(pk[i] >> 17) & (BW - 1)], 1);
  __syncthreads();
  int c0 = sc[t], c1 = sc[t + 1024];
  // inclusive scan sc[0..BW)
  for (int d = 1; d < BW; d <<= 1) {
    int v0 = (t >= d) ? sc[t - d] : 0;
    int v1 = (t + 1024 >= d) ? sc[t + 1024 - d] : 0;
    __syncthreads();
    sc[t] += v0; sc[t + 1024] += v1;
    __syncthreads();
  }
  int ex0 = sc[t] - c0, ex1 = sc[t + 1024] - c1;
  int na = node0 + t, nbn = node0 + t + 1024;
  if (na < n)  { off[na]  = e0 + ex0; dinv[na]  = rsqrtf((float)c0 + 1.0f); }
  if (nbn < n) { off[nbn] = e0 + ex1; dinv[nbn] = rsqrtf((float)c1 + 1.0f); }
  __syncthreads();
  sc[t] = ex0; sc[t + 1024] = ex1;
  __syncthreads();
  for (int i = e0 + t; i < e1; i += 1024) {
    int v = pk[i];
    int dl = (v >> 17) & (BW - 1);
    int p = atomicAdd(&lcur[dl], 1);
    csr[e0 + sc[dl] + p] = v & 0x1FFFF;
  }
}

// ================= GEMM: Asb(bf16) = (act(X)@W) * dinv[row] =================
template <bool RELU_BIAS>
__global__ __launch_bounds__(128)
void k_gemm(const float* __restrict__ X, const float* __restrict__ W,
            const float* __restrict__ bias, const float* __restrict__ dinv,
            ushort* __restrict__ Asb, int n) {
  __shared__ __align__(16) float Xt[128 * 68];
  const int tid = threadIdx.x;
  const int row0 = blockIdx.x * 64;

#pragma unroll
  for (int i = 0; i < 16; ++i) {
    int f = i * 128 + tid;
    int rl = f >> 5;
    int k0 = (f & 31) * 4;
    int row = row0 + rl;
    float4 v = make_float4(0.f, 0.f, 0.f, 0.f);
    if (row < n) {
      v = *(const float4*)(X + (size_t)row * D + k0);
      if (RELU_BIAS) {
        float4 b = *(const float4*)(bias + k0);
        v.x = fmaxf(v.x + b.x, 0.f);
        v.y = fmaxf(v.y + b.y, 0.f);
        v.z = fmaxf(v.z + b.z, 0.f);
        v.w = fmaxf(v.w + b.w, 0.f);
      }
    }
    Xt[(k0 + 0) * 68 + rl] = v.x;
    Xt[(k0 + 1) * 68 + rl] = v.y;
    Xt[(k0 + 2) * 68 + rl] = v.z;
    Xt[(k0 + 3) * 68 + rl] = v.w;
  }
  __syncthreads();

  const int rg = tid >> 4;
  const int cg = tid & 15;
  float acc[8][8];
#pragma unroll
  for (int i = 0; i < 8; ++i)
#pragma unroll
    for (int j = 0; j < 8; ++j) acc[i][j] = 0.f;

  const float* Wp = W + cg * 8;
#pragma unroll 4
  for (int k = 0; k < 128; ++k) {
    float xv[8], wv[8];
    *(float4*)(xv)     = *(const float4*)(Xt + k * 68 + rg * 8);
    *(float4*)(xv + 4) = *(const float4*)(Xt + k * 68 + rg * 8 + 4);
    *(float4*)(wv)     = *(const float4*)(Wp + (size_t)k * D);
    *(float4*)(wv + 4) = *(const float4*)(Wp + (size_t)k * D + 4);
#pragma unroll
    for (int i = 0; i < 8; ++i)
#pragma unroll
      for (int j = 0; j < 8; ++j)
        acc[i][j] = fmaf(xv[i], wv[j], acc[i][j]);
  }

#pragma unroll
  for (int i = 0; i < 8; ++i) {
    int row = row0 + rg * 8 + i;
    if (row >= n) break;
    float di = dinv[row];
    uint4 w;
    w.x = pack2(acc[i][0] * di, acc[i][1] * di);
    w.y = pack2(acc[i][2] * di, acc[i][3] * di);
    w.z = pack2(acc[i][4] * di, acc[i][5] * di);
    w.w = pack2(acc[i][6] * di, acc[i][7] * di);
    *(uint4*)(Asb + (size_t)row * D + cg * 8) = w;
  }
}

// ================= gather aggregate =================
template <bool FUSE_DOT>
__global__ __launch_bounds__(256)
void k_gather(const int* __restrict__ off, const int* __restrict__ csr,
              const float* __restrict__ dinv, const ushort* __restrict__ Asb,
              float* __restrict__ B, const float* __restrict__ b1,
              const float* __restrict__ W2, float* __restrict__ ss, int n) {
  const int wid = blockIdx.x * 4 + (threadIdx.x >> 6);
  if (wid >= n) return;
  const int lane = threadIdx.x & 63;
  const int q = lane >> 4;
  const int li = lane & 15;
  const int c = li << 3;

  float a[8];
#pragma unroll
  for (int k = 0; k < 8; ++k) a[k] = 0.f;
  if (q == 0) {
    uint4 sv = *(const uint4*)(Asb + (size_t)wid * D + c);
    acc_bf16x8(sv, a);
  }

  const int o0 = off[wid], o1 = off[wid + 1];
  for (int j0 = o0; j0 < o1; j0 += 64) {
    int sj = 0;
    if (j0 + lane < o1) sj = csr[j0 + lane];
    const int m = min(64, o1 - j0);
    const int nst = (m + 3) >> 2;
#pragma unroll 4
    for (int t = 0; t < nst; ++t) {
      int idx = (t << 2) + q;
      int s = __shfl(sj, idx);
      if (idx < m) {
        uint4 v = *(const uint4*)(Asb + (size_t)s * D + c);
        acc_bf16x8(v, a);
      }
    }
  }

#pragma unroll
  for (int k = 0; k < 8; ++k) {
    a[k] += __shfl_xor(a[k], 16);
    a[k] += __shfl_xor(a[k], 32);
  }

  const float di = dinv[wid];
  if (FUSE_DOT) {
    float4 bb0 = *(const float4*)(b1 + c);
    float4 bb1 = *(const float4*)(b1 + c + 4);
    float4 w0 = *(const float4*)(W2 + c);
    float4 w1 = *(const float4*)(W2 + c + 4);
    float p = 0.f;
    p += fmaxf(a[0] * di + bb0.x, 0.f) * w0.x;
    p += fmaxf(a[1] * di + bb0.y, 0.f) * w0.y;
    p += fmaxf(a[2] * di + bb0.z, 0.f) * w0.z;
    p += fmaxf(a[3] * di + bb0.w, 0.f) * w0.w;
    p += fmaxf(a[4] * di + bb1.x, 0.f) * w1.x;
    p += fmaxf(a[5] * di + bb1.y, 0.f) * w1.y;
    p += fmaxf(a[6] * di + bb1.z, 0.f) * w1.z;
    p += fmaxf(a[7] * di + bb1.w, 0.f) * w1.w;
    p += __shfl_xor(p, 1);
    p += __shfl_xor(p, 2);
    p += __shfl_xor(p, 4);
    p += __shfl_xor(p, 8);
    if (lane == 0) ss[wid] = p * di;
  } else {
    if (lane < 16) {
      float4 o0v = make_float4(a[0] * di, a[1] * di, a[2] * di, a[3] * di);
      float4 o1v = make_float4(a[4] * di, a[5] * di, a[6] * di, a[7] * di);
      *(float4*)(B + (size_t)wid * D + c)     = o0v;
      *(float4*)(B + (size_t)wid * D + c + 4) = o1v;
    }
  }
}

// ================= scalar gather + sigmoid =================
__global__ void k_gather_scalar(const int* __restrict__ off, const int* __restrict__ csr,
                                const float* __restrict__ dinv, const float* __restrict__ ss,
                                const float* __restrict__ b2, float* __restrict__ out, int n) {
  int i = blockIdx.x * 256 + threadIdx.x;
  if (i >= n) return;
  float acc = ss[i];
  int j = off[i], o1 = off[i + 1];
  float a0 = 0.f, a1 = 0.f, a2 = 0.f, a3 = 0.f;
  for (; j + 4 <= o1; j += 4) {
    int s0 = csr[j], s1 = csr[j + 1], s2 = csr[j + 2], s3 = csr[j + 3];
    a0 += ss[s0];
    a1 += ss[s1];
    a2 += ss[s2];
    a3 += ss[s3];
  }
  for (; j < o1; ++j) a0 += ss[csr[j]];
  acc += (a0 + a1) + (a2 + a3);
  float v = acc * dinv[i] + b2[0];
  out[i] = 1.f / (1.f + expf(-v));
}

// ================= launch =================
extern "C" void kernel_launch(void* const* d_in, const int* in_sizes, int n_in,
                              void* d_out, int out_size, void* d_ws, size_t ws_size,
                              hipStream_t stream) {
  const float* x  = (const float*)d_in[0];
  const int*   ei = (const int*)d_in[1];   // int64 in source collapses to int32 (JAX x64 off)
  const float* W0 = (const float*)d_in[2];
  const float* b0 = (const float*)d_in[3];
  const float* W1 = (const float*)d_in[4];
  const float* b1 = (const float*)d_in[5];
  const float* W2 = (const float*)d_in[6];
  const float* b2 = (const float*)d_in[7];
  float* out = (float*)d_out;

  const int n = in_sizes[0] / D;
  const int e = in_sizes[1] / 2;
  const int nb = (n + BW - 1) / BW;                 // buckets (<=256; n=100000 -> 49)
  const size_t np = ((size_t)n + 256) / 256 * 256;  // holds n+1, 256-aligned

  float* ws = (float*)d_ws;
  int*    off    = (int*)ws;                         // np
  float*  dinv   = ws + np;                          // np
  float*  ss     = ws + 2 * np;                      // np
  int*    bmeta  = (int*)(ws + 3 * np);              // 1024: bcnt|bbase|cursor
  int*    bcnt   = bmeta;
  int*    bbase  = bmeta + 260;
  int*    cursor = bmeta + 600;
  int*    csr    = (int*)(ws + 3 * np + 1024);       // e
  int*    pk     = csr + e;                          // e
  ushort* Asb    = (ushort*)(pk + e);                // n*D bf16
  float*  B      = (float*)(Asb + (size_t)n * D);    // n*D f32

  const int g256n = (n + 255) / 256;
  const int ggemm = (n + 63) / 64;
  const int ggath = (n + 3) / 4;
  const int gchnk = (e + CHUNK - 1) / CHUNK;

  // ---- bucketed CSR build ----
  k_bzero<<<1, 256, 0, stream>>>(bcnt, nb);
  k_bhist<<<gchnk, 512, 0, stream>>>(ei + e, bcnt, e, nb);
  k_bscan<<<1, 256, 0, stream>>>(bcnt, bbase, cursor, off, nb, n, e);
  k_bscatter<<<gchnk, 512, 0, stream>>>(ei, cursor, pk, e, nb);
  k_bfinal<<<nb, 1024, 0, stream>>>(bbase, pk, off, dinv, csr, n, nb);

  // ---- layer 0 ----
  k_gemm<false><<<ggemm, 128, 0, stream>>>(x, W0, nullptr, dinv, Asb, n);
  k_gather<false><<<ggath, 256, 0, stream>>>(off, csr, dinv, Asb, B, nullptr, nullptr, nullptr, n);

  // ---- layer 1 + fused layer-2 GEMV ----
  k_gemm<true><<<ggemm, 128, 0, stream>>>(B, W1, b0, dinv, Asb, n);
  k_gather<true><<<ggath, 256, 0, stream>>>(off, csr, dinv, Asb, nullptr, b1, W2, ss, n);

  // ---- scalar aggregate + sigmoid ----
  k_gather_scalar<<<g256n, 256, 0, stream>>>(off, csr, dinv, ss, b2, out, n);
}

// Round 5
// 294.767 us; speedup vs baseline: 19.2850x; 1.1791x over previous
//
#include <hip/hip_runtime.h>
#include <cstddef>

#define D 128
#define BW_LOG 11
#define BW 2048            // nodes per bucket (NB = ceil(n/BW) <= 256 required)
#define CHUNK 8192         // edges per bscatter/bhist block
#define GP 136             // LDS pitch (ushorts) for W tiles: 272B, 16B-aligned, 2-way banks
typedef unsigned int uint;
typedef unsigned short ushort;

typedef __attribute__((ext_vector_type(8))) short bf16x8;
typedef __attribute__((ext_vector_type(4))) float f32x4;

// ---- bf16 helpers (RNE) ----
static __device__ __forceinline__ uint bf16r(float x) {
  uint u = __float_as_uint(x);
  return (u + 0x7fffu + ((u >> 16) & 1u)) >> 16;
}
static __device__ __forceinline__ uint pack2(float a, float b) {
  return bf16r(a) | (bf16r(b) << 16);
}
static __device__ __forceinline__ void acc_bf16x8(const uint4 v, float* a) {
  a[0] += __uint_as_float(v.x << 16);
  a[1] += __uint_as_float(v.x & 0xffff0000u);
  a[2] += __uint_as_float(v.y << 16);
  a[3] += __uint_as_float(v.y & 0xffff0000u);
  a[4] += __uint_as_float(v.z << 16);
  a[5] += __uint_as_float(v.z & 0xffff0000u);
  a[6] += __uint_as_float(v.w << 16);
  a[7] += __uint_as_float(v.w & 0xffff0000u);
}

// ================= bucketed CSR build =================
__global__ void k_bzero(int* __restrict__ bcnt, int nb) {
  int t = threadIdx.x;
  if (t < nb) bcnt[t] = 0;
}

__global__ __launch_bounds__(512)
void k_bhist(const int* __restrict__ dstA, int* __restrict__ bcnt, int e, int nb) {
  __shared__ int h[256];
  int t = threadIdx.x;
  if (t < nb) h[t] = 0;
  __syncthreads();
  int base = blockIdx.x * CHUNK;
  int m = min(CHUNK, e - base);
  for (int i = t; i < m; i += 512) atomicAdd(&h[dstA[base + i] >> BW_LOG], 1);
  __syncthreads();
  if (t < nb && h[t]) atomicAdd(&bcnt[t], h[t]);
}

__global__ void k_bscan(const int* __restrict__ bcnt, int* __restrict__ bbase,
                        int* __restrict__ cursor, int* __restrict__ off,
                        int nb, int n, int e) {
  __shared__ int s[256];
  int t = threadIdx.x;
  int v = (t < nb) ? bcnt[t] : 0;
  s[t] = v;
  __syncthreads();
  for (int d = 1; d < 256; d <<= 1) {
    int x = (t >= d) ? s[t - d] : 0;
    __syncthreads();
    s[t] += x;
    __syncthreads();
  }
  if (t < nb) {
    int b = s[t] - v;
    bbase[t] = b;
    cursor[t] = b;
  }
  if (t == 0) {
    bbase[nb] = e;
    off[n] = e;
  }
}

__global__ __launch_bounds__(512)
void k_bscatter(const int* __restrict__ ei, int* __restrict__ cursor,
                int* __restrict__ pk, int e, int nb) {
  __shared__ int h[256], lbase[256], gpos[256], lcur[256], s2[256];
  __shared__ int staged[CHUNK];
  int t = threadIdx.x;
  if (t < nb) h[t] = 0;
  __syncthreads();
  int base = blockIdx.x * CHUNK;
  int m = min(CHUNK, e - base);
  int sv[16], dv[16];
#pragma unroll
  for (int k = 0; k < 16; ++k) {
    int i = t + k * 512;
    sv[k] = 0; dv[k] = 0;
    if (i < m) {
      sv[k] = ei[base + i];
      dv[k] = ei[e + base + i];
      atomicAdd(&h[dv[k] >> BW_LOG], 1);
    }
  }
  __syncthreads();
  if (t < 256) s2[t] = (t < nb) ? h[t] : 0;
  __syncthreads();
  for (int d = 1; d < 256; d <<= 1) {
    int x = 0;
    if (t < 256 && t >= d) x = s2[t - d];
    __syncthreads();
    if (t < 256) s2[t] += x;
    __syncthreads();
  }
  if (t < nb) {
    lbase[t] = s2[t] - h[t];
    lcur[t] = s2[t] - h[t];
    gpos[t] = h[t] ? atomicAdd(&cursor[t], h[t]) : 0;
  }
  __syncthreads();
#pragma unroll
  for (int k = 0; k < 16; ++k) {
    int i = t + k * 512;
    if (i < m) {
      int b = dv[k] >> BW_LOG;
      int p = atomicAdd(&lcur[b], 1);
      staged[p] = sv[k] | ((dv[k] & (BW - 1)) << 17);
    }
  }
  __syncthreads();
  for (int b = 0; b < nb; ++b) {
    int cnt = h[b], lb = lbase[b], gp = gpos[b];
    for (int i = t; i < cnt; i += 512) pk[gp + i] = staged[lb + i];
  }
}

__global__ __launch_bounds__(1024)
void k_bfinal(const int* __restrict__ bbase, const int* __restrict__ pk,
              int* __restrict__ off, float* __restrict__ dinv,
              int* __restrict__ csr, int n, int nb) {
  __shared__ int sc[BW];
  __shared__ int lcur[BW];
  const int b = blockIdx.x;
  const int t = threadIdx.x;
  const int e0 = bbase[b], e1 = bbase[b + 1];
  const int node0 = b << BW_LOG;
  sc[t] = 0; sc[t + 1024] = 0;
  lcur[t] = 0; lcur[t + 1024] = 0;
  __syncthreads();
  for (int i = e0 + t; i < e1; i += 1024) atomicAdd(&sc[(pk[i] >> 17) & (BW - 1)], 1);
  __syncthreads();
  int c0 = sc[t], c1 = sc[t + 1024];
  for (int d = 1; d < BW; d <<= 1) {
    int v0 = (t >= d) ? sc[t - d] : 0;
    int v1 = (t + 1024 >= d) ? sc[t + 1024 - d] : 0;
    __syncthreads();
    sc[t] += v0; sc[t + 1024] += v1;
    __syncthreads();
  }
  int ex0 = sc[t] - c0, ex1 = sc[t + 1024] - c1;
  int na = node0 + t, nbn = node0 + t + 1024;
  if (na < n)  { off[na]  = e0 + ex0; dinv[na]  = rsqrtf((float)c0 + 1.0f); }
  if (nbn < n) { off[nbn] = e0 + ex1; dinv[nbn] = rsqrtf((float)c1 + 1.0f); }
  __syncthreads();
  sc[t] = ex0; sc[t + 1024] = ex1;
  __syncthreads();
  for (int i = e0 + t; i < e1; i += 1024) {
    int v = pk[i];
    int dl = (v >> 17) & (BW - 1);
    int p = atomicAdd(&lcur[dl], 1);
    csr[e0 + sc[dl] + p] = v & 0x1FFFF;
  }
}

// ================= MFMA GEMM: Asb(bf16) = (act(X)@W) * dinv[row] =================
// Split precision: X = Ahi+Alo (bf16 pair), W = Whi+Wlo (bf16 pair in LDS).
// 3 MFMA terms per tile: ~f32 accuracy at bf16 MFMA rate.
// Block = 256 thr (4 waves). W staged once into LDS; grid-stride over 16-row
// strips (one strip per wave per iter). No transpose of A needed: MFMA A-frag
// for 16x16x32 is 8 consecutive k per lane (row = lane&15).
template <bool RELU_BIAS>
__global__ __launch_bounds__(256)
void k_mgemm(const float* __restrict__ X, const float* __restrict__ W,
             const float* __restrict__ bias, const float* __restrict__ dinv,
             ushort* __restrict__ Asb, int n, int nstrips) {
  __shared__ __align__(16) ushort Wh[128 * GP];
  __shared__ __align__(16) ushort Wl[128 * GP];
  const int tid = threadIdx.x;

  // stage W transposed: Wt[n][k], hi+lo. Thread i -> (nn=i&127, k0=(i>>7)*4).
  // Global loads coalesced along n; LDS writes b64, lane bank-stride 4 (clean).
  for (int i = tid; i < 4096; i += 256) {
    int nn = i & 127;
    int k0 = (i >> 7) * 4;
    union { ushort4 v; ushort a[4]; } h, l;
#pragma unroll
    for (int r = 0; r < 4; ++r) {
      float w = W[(size_t)(k0 + r) * D + nn];
      uint hb = bf16r(w);
      float hf = __uint_as_float(hb << 16);
      h.a[r] = (ushort)hb;
      l.a[r] = (ushort)bf16r(w - hf);
    }
    *(ushort4*)(&Wh[nn * GP + k0]) = h.v;
    *(ushort4*)(&Wl[nn * GP + k0]) = l.v;
  }
  __syncthreads();

  const int wv = tid >> 6;
  const int l = tid & 63;
  const int lr = l & 15;        // A-row / B-col within tile
  const int lk = (l >> 4) * 8;  // k sub-offset

  for (int strip = blockIdx.x * 4 + wv; strip < nstrips; strip += gridDim.x * 4) {
    const int row0 = strip * 16;
    f32x4 acc[8];
#pragma unroll
    for (int t = 0; t < 8; ++t) acc[t] = (f32x4){0.f, 0.f, 0.f, 0.f};

    const int arow = row0 + lr;
    const bool av = (arow < n);
    const float* ap = X + (size_t)arow * D;

#pragma unroll
    for (int ks = 0; ks < 4; ++ks) {
      const int k0 = ks * 32 + lk;
      float a8[8];
      if (av) {
        float4 u0 = *(const float4*)(ap + k0);
        float4 u1 = *(const float4*)(ap + k0 + 4);
        a8[0] = u0.x; a8[1] = u0.y; a8[2] = u0.z; a8[3] = u0.w;
        a8[4] = u1.x; a8[5] = u1.y; a8[6] = u1.z; a8[7] = u1.w;
        if (RELU_BIAS) {
          float4 b0v = *(const float4*)(bias + k0);
          float4 b1v = *(const float4*)(bias + k0 + 4);
          a8[0] = fmaxf(a8[0] + b0v.x, 0.f);
          a8[1] = fmaxf(a8[1] + b0v.y, 0.f);
          a8[2] = fmaxf(a8[2] + b0v.z, 0.f);
          a8[3] = fmaxf(a8[3] + b0v.w, 0.f);
          a8[4] = fmaxf(a8[4] + b1v.x, 0.f);
          a8[5] = fmaxf(a8[5] + b1v.y, 0.f);
          a8[6] = fmaxf(a8[6] + b1v.z, 0.f);
          a8[7] = fmaxf(a8[7] + b1v.w, 0.f);
        }
      } else {
#pragma unroll
        for (int j = 0; j < 8; ++j) a8[j] = 0.f;
      }
      union { bf16x8 v; ushort a[8]; } ah, al;
#pragma unroll
      for (int j = 0; j < 8; ++j) {
        uint hb = bf16r(a8[j]);
        float hf = __uint_as_float(hb << 16);
        ah.a[j] = (ushort)hb;
        al.a[j] = (ushort)bf16r(a8[j] - hf);
      }
#pragma unroll
      for (int nt = 0; nt < 8; ++nt) {
        bf16x8 bh = *(const bf16x8*)(&Wh[(nt * 16 + lr) * GP + k0]);
        bf16x8 bl = *(const bf16x8*)(&Wl[(nt * 16 + lr) * GP + k0]);
        acc[nt] = __builtin_amdgcn_mfma_f32_16x16x32_bf16(ah.v, bh, acc[nt], 0, 0, 0);
        acc[nt] = __builtin_amdgcn_mfma_f32_16x16x32_bf16(al.v, bh, acc[nt], 0, 0, 0);
        acc[nt] = __builtin_amdgcn_mfma_f32_16x16x32_bf16(ah.v, bl, acc[nt], 0, 0, 0);
      }
    }

    // epilogue: C/D layout col=lane&15, row=(lane>>4)*4+reg
#pragma unroll
    for (int r = 0; r < 4; ++r) {
      int row = row0 + (l >> 4) * 4 + r;
      if (row < n) {
        float di = dinv[row];
#pragma unroll
        for (int nt = 0; nt < 8; ++nt) {
          Asb[(size_t)row * D + nt * 16 + lr] = (ushort)bf16r(acc[nt][r] * di);
        }
      }
    }
  }
}

// ================= gather aggregate =================
template <bool FUSE_DOT>
__global__ __launch_bounds__(256)
void k_gather(const int* __restrict__ off, const int* __restrict__ csr,
              const float* __restrict__ dinv, const ushort* __restrict__ Asb,
              float* __restrict__ B, const float* __restrict__ b1,
              const float* __restrict__ W2, float* __restrict__ ss, int n) {
  const int wid = blockIdx.x * 4 + (threadIdx.x >> 6);
  if (wid >= n) return;
  const int lane = threadIdx.x & 63;
  const int q = lane >> 4;
  const int li = lane & 15;
  const int c = li << 3;

  float a[8];
#pragma unroll
  for (int k = 0; k < 8; ++k) a[k] = 0.f;
  if (q == 0) {
    uint4 sv = *(const uint4*)(Asb + (size_t)wid * D + c);
    acc_bf16x8(sv, a);
  }

  const int o0 = off[wid], o1 = off[wid + 1];
  for (int j0 = o0; j0 < o1; j0 += 64) {
    int sj = 0;
    if (j0 + lane < o1) sj = csr[j0 + lane];
    const int m = min(64, o1 - j0);
    const int nst = (m + 3) >> 2;
#pragma unroll 4
    for (int t = 0; t < nst; ++t) {
      int idx = (t << 2) + q;
      int s = __shfl(sj, idx);
      if (idx < m) {
        uint4 v = *(const uint4*)(Asb + (size_t)s * D + c);
        acc_bf16x8(v, a);
      }
    }
  }

#pragma unroll
  for (int k = 0; k < 8; ++k) {
    a[k] += __shfl_xor(a[k], 16);
    a[k] += __shfl_xor(a[k], 32);
  }

  const float di = dinv[wid];
  if (FUSE_DOT) {
    float4 bb0 = *(const float4*)(b1 + c);
    float4 bb1 = *(const float4*)(b1 + c + 4);
    float4 w0 = *(const float4*)(W2 + c);
    float4 w1 = *(const float4*)(W2 + c + 4);
    float p = 0.f;
    p += fmaxf(a[0] * di + bb0.x, 0.f) * w0.x;
    p += fmaxf(a[1] * di + bb0.y, 0.f) * w0.y;
    p += fmaxf(a[2] * di + bb0.z, 0.f) * w0.z;
    p += fmaxf(a[3] * di + bb0.w, 0.f) * w0.w;
    p += fmaxf(a[4] * di + bb1.x, 0.f) * w1.x;
    p += fmaxf(a[5] * di + bb1.y, 0.f) * w1.y;
    p += fmaxf(a[6] * di + bb1.z, 0.f) * w1.z;
    p += fmaxf(a[7] * di + bb1.w, 0.f) * w1.w;
    p += __shfl_xor(p, 1);
    p += __shfl_xor(p, 2);
    p += __shfl_xor(p, 4);
    p += __shfl_xor(p, 8);
    if (lane == 0) ss[wid] = p * di;
  } else {
    if (lane < 16) {
      float4 o0v = make_float4(a[0] * di, a[1] * di, a[2] * di, a[3] * di);
      float4 o1v = make_float4(a[4] * di, a[5] * di, a[6] * di, a[7] * di);
      *(float4*)(B + (size_t)wid * D + c)     = o0v;
      *(float4*)(B + (size_t)wid * D + c + 4) = o1v;
    }
  }
}

// ================= scalar gather + sigmoid =================
__global__ void k_gather_scalar(const int* __restrict__ off, const int* __restrict__ csr,
                                const float* __restrict__ dinv, const float* __restrict__ ss,
                                const float* __restrict__ b2, float* __restrict__ out, int n) {
  int i = blockIdx.x * 256 + threadIdx.x;
  if (i >= n) return;
  float acc = ss[i];
  int j = off[i], o1 = off[i + 1];
  float a0 = 0.f, a1 = 0.f, a2 = 0.f, a3 = 0.f;
  for (; j + 4 <= o1; j += 4) {
    int s0 = csr[j], s1 = csr[j + 1], s2 = csr[j + 2], s3 = csr[j + 3];
    a0 += ss[s0];
    a1 += ss[s1];
    a2 += ss[s2];
    a3 += ss[s3];
  }
  for (; j < o1; ++j) a0 += ss[csr[j]];
  acc += (a0 + a1) + (a2 + a3);
  float v = acc * dinv[i] + b2[0];
  out[i] = 1.f / (1.f + expf(-v));
}

// ================= launch =================
extern "C" void kernel_launch(void* const* d_in, const int* in_sizes, int n_in,
                              void* d_out, int out_size, void* d_ws, size_t ws_size,
                              hipStream_t stream) {
  const float* x  = (const float*)d_in[0];
  const int*   ei = (const int*)d_in[1];   // int64 in source collapses to int32 (JAX x64 off)
  const float* W0 = (const float*)d_in[2];
  const float* b0 = (const float*)d_in[3];
  const float* W1 = (const float*)d_in[4];
  const float* b1 = (const float*)d_in[5];
  const float* W2 = (const float*)d_in[6];
  const float* b2 = (const float*)d_in[7];
  float* out = (float*)d_out;

  const int n = in_sizes[0] / D;
  const int e = in_sizes[1] / 2;
  const int nb = (n + BW - 1) / BW;                 // buckets (n=100000 -> 49)
  const int nstrips = (n + 15) / 16;
  const size_t np = ((size_t)n + 256) / 256 * 256;  // holds n+1, 256-aligned

  float* ws = (float*)d_ws;
  int*    off    = (int*)ws;                         // np
  float*  dinv   = ws + np;                          // np
  float*  ss     = ws + 2 * np;                      // np
  int*    bmeta  = (int*)(ws + 3 * np);              // 1024: bcnt|bbase|cursor
  int*    bcnt   = bmeta;
  int*    bbase  = bmeta + 260;
  int*    cursor = bmeta + 600;
  int*    csr    = (int*)(ws + 3 * np + 1024);       // e
  int*    pk     = csr + e;                          // e
  ushort* Asb    = (ushort*)(pk + e);                // n*D bf16
  float*  B      = (float*)(Asb + (size_t)n * D);    // n*D f32

  const int g256n = (n + 255) / 256;
  const int ggath = (n + 3) / 4;
  const int gchnk = (e + CHUNK - 1) / CHUNK;

  // ---- bucketed CSR build ----
  k_bzero<<<1, 256, 0, stream>>>(bcnt, nb);
  k_bhist<<<gchnk, 512, 0, stream>>>(ei + e, bcnt, e, nb);
  k_bscan<<<1, 256, 0, stream>>>(bcnt, bbase, cursor, off, nb, n, e);
  k_bscatter<<<gchnk, 512, 0, stream>>>(ei, cursor, pk, e, nb);
  k_bfinal<<<nb, 1024, 0, stream>>>(bbase, pk, off, dinv, csr, n, nb);

  // ---- layer 0 ----
  k_mgemm<false><<<512, 256, 0, stream>>>(x, W0, nullptr, dinv, Asb, n, nstrips);
  k_gather<false><<<ggath, 256, 0, stream>>>(off, csr, dinv, Asb, B, nullptr, nullptr, nullptr, n);

  // ---- layer 1 + fused layer-2 GEMV ----
  k_mgemm<true><<<512, 256, 0, stream>>>(B, W1, b0, dinv, Asb, n, nstrips);
  k_gather<true><<<ggath, 256, 0, stream>>>(off, csr, dinv, Asb, nullptr, b1, W2, ss, n);

  // ---- scalar aggregate + sigmoid ----
  k_gather_scalar<<<g256n, 256, 0, stream>>>(off, csr, dinv, ss, b2, out, n);
}